// Round 4
// baseline (897.586 us; speedup 1.0000x reference)
//
#include <hip/hip_runtime.h>

#define B_ 64
#define S_ 8
#define F_ 4096
#define DIN_ 256
#define D_ 64
#define H_ 256
#define FT_ 256    // features per attention tile
#define NB2_ 512   // k_iter grid; co-residency: LDS 45056*2=90112<160K/CU, VGPR<=256 via launch_bounds

typedef unsigned short ushort_t;
typedef __attribute__((ext_vector_type(8))) short bf16x8;
typedef __attribute__((ext_vector_type(4))) float f32x4;

__device__ __forceinline__ float bflo(unsigned int u){ union{unsigned int i; float f;} v; v.i = u<<16; return v.f; }
__device__ __forceinline__ float bfhi(unsigned int u){ union{unsigned int i; float f;} v; v.i = u & 0xffff0000u; return v.f; }
__device__ __forceinline__ float bf2f(ushort_t s){ union{unsigned int i; float f;} v; v.i = ((unsigned int)s)<<16; return v.f; }
__device__ __forceinline__ ushort_t f2bf(float f){ union{float f; unsigned int i;} v; v.f = f; unsigned int u = v.i; u += 0x7fffu + ((u>>16)&1u); return (ushort_t)(u>>16); }

// Coherent (agent-scope, cache-point) accesses for cross-block mailboxes.
__device__ __forceinline__ float agload(const float* p){
  return __hip_atomic_load(p, __ATOMIC_RELAXED, __HIP_MEMORY_SCOPE_AGENT);
}
__device__ __forceinline__ void agstore(float* p, float v){
  __hip_atomic_store(p, v, __ATOMIC_RELAXED, __HIP_MEMORY_SCOPE_AGENT);
}

#define DOT8(u, xp, acc) \
  acc += bflo((u).x)*(xp)[0]+bfhi((u).x)*(xp)[1]+bflo((u).y)*(xp)[2]+bfhi((u).y)*(xp)[3] \
       + bflo((u).z)*(xp)[4]+bfhi((u).z)*(xp)[5]+bflo((u).w)*(xp)[6]+bfhi((u).w)*(xp)[7]

// dtype-dual scalar load of logical fp32 element i
__device__ __forceinline__ float ldf(const void* p, int i, int bf){
  return bf ? bf2f(((const ushort_t*)p)[i]) : ((const float*)p)[i];
}

// dtype-dual dot of row W[base..base+n8*8) with x[0..n8*8)
__device__ __forceinline__ float dotN(const void* W, size_t base, const float* x, int n8, int bf){
  float acc = 0.f;
  if (bf){
    const uint4* wr = (const uint4*)((const ushort_t*)W + base);
    #pragma unroll
    for (int c=0;c<n8;c++){ uint4 u = wr[c]; const float* xp = x + c*8; DOT8(u, xp, acc); }
  } else {
    const float4* wr = (const float4*)((const float*)W + base);
    #pragma unroll
    for (int c=0;c<n8*2;c++){
      float4 wv = wr[c]; const float* xp = x + c*4;
      acc += wv.x*xp[0]+wv.y*xp[1]+wv.z*xp[2]+wv.w*xp[3];
    }
  }
  return acc;
}

// two dots sharing one weight row (per-dot summation order identical to dotN)
__device__ __forceinline__ void dot2(const void* W, size_t base, const float* x0, const float* x1,
                                     int n8, int bf, float& r0, float& r1){
  float a0 = 0.f, a1 = 0.f;
  if (bf){
    const uint4* wr = (const uint4*)((const ushort_t*)W + base);
    #pragma unroll
    for (int c=0;c<n8;c++){
      uint4 u = wr[c];
      DOT8(u, x0 + c*8, a0);
      DOT8(u, x1 + c*8, a1);
    }
  } else {
    const float4* wr = (const float4*)((const float*)W + base);
    #pragma unroll
    for (int c=0;c<n8*2;c++){
      float4 wv = wr[c];
      const float* p0 = x0 + c*4; const float* p1 = x1 + c*4;
      a0 += wv.x*p0[0]+wv.y*p0[1]+wv.z*p0[2]+wv.w*p0[3];
      a1 += wv.x*p1[0]+wv.y*p1[1]+wv.z*p1[2]+wv.w*p1[3];
    }
  }
  r0 = a0; r1 = a1;
}

// ---------------------------------------------------------------------------
// FENCE-FREE grid barrier (proven round 3). Monotonic arrive counter.
// ---------------------------------------------------------------------------
__device__ __forceinline__ void gsync(unsigned int* bar){
  __syncthreads();
  if (threadIdx.x == 0){
    unsigned int t = __hip_atomic_fetch_add(bar, 1u, __ATOMIC_RELAXED, __HIP_MEMORY_SCOPE_AGENT);
    const unsigned int target = (t/(unsigned)NB2_ + 1u) * (unsigned)NB2_;
    unsigned int spins = 0;
    while (__hip_atomic_load(bar, __ATOMIC_RELAXED, __HIP_MEMORY_SCOPE_AGENT) < target){
      __builtin_amdgcn_s_sleep(8);
      if (++spins > 5000000u) break;   // failsafe: never hang the harness
    }
  }
  __syncthreads();
}

// ---------------------------------------------------------------------------
__global__ __launch_bounds__(256) void k_sentinel(ushort_t* __restrict__ out_slots,
                                                  ushort_t* __restrict__ out_attn, float val)
{
  const int i = blockIdx.x*256 + threadIdx.x;
  if (i < B_*S_*D_) out_slots[i] = f2bf(val);
  for (int j = i; j < B_*S_*F_; j += gridDim.x*256) out_attn[j] = 0;
}

// ---------------------------------------------------------------------------
// Kernel 1 (round-0 proven, 2048 blocks): LN(features) + [K|V] proj via MFMA.
// Block 0 zeroes the grid-barrier counter for k_iter.
// ---------------------------------------------------------------------------
__global__ __launch_bounds__(256) void k_lnproj(
    const void* __restrict__ feats, const void* __restrict__ gf, const void* __restrict__ bfp,
    const void* __restrict__ Wk, const void* __restrict__ Wv,
    ushort_t* __restrict__ Kout, ushort_t* __restrict__ Vout, unsigned int* __restrict__ bar)
{
  __shared__ ushort_t smem[16384];
  __shared__ float gf_s[256], bf_s[256];
  const int bf = (*(const unsigned int*)gf == 0x3F803F80u);
  const int tid = threadIdx.x;
  const int lane = tid & 63, w = tid >> 6;
  if (blockIdx.x == 0 && tid == 0) *bar = 0u;   // visible at kernel boundary
  if (tid < 256){ gf_s[tid] = ldf(gf, tid, bf); bf_s[tid] = ldf(bfp, tid, bf); }
  bf16x8 wreg[2][8];
  #pragma unroll
  for (int nf=0; nf<2; nf++){
    const int n = w*32 + nf*16 + (lane&15);
    if (bf){
      const ushort_t* wrow = (n < 64) ? ((const ushort_t*)Wk + n*DIN_)
                                      : ((const ushort_t*)Wv + (n-64)*DIN_);
      #pragma unroll
      for (int kt=0; kt<8; kt++)
        wreg[nf][kt] = *(const bf16x8*)(wrow + kt*32 + ((lane>>4)<<3));
    } else {
      const float* wrow = (n < 64) ? ((const float*)Wk + n*DIN_)
                                   : ((const float*)Wv + (n-64)*DIN_);
      #pragma unroll
      for (int kt=0; kt<8; kt++){
        const float* wp = wrow + kt*32 + ((lane>>4)<<3);
        bf16x8 t;
        #pragma unroll
        for (int j=0;j<8;j++) t[j] = (short)f2bf(wp[j]);
        wreg[nf][kt] = t;
      }
    }
  }
  __syncthreads();
  const int r = tid >> 2, qt = tid & 3;
  for (int tile = blockIdx.x; tile < 4096; tile += gridDim.x){
    const int m0 = tile*64;
    float vals[64];
    if (bf){
      const uint4* src = (const uint4*)((const ushort_t*)feats + (size_t)(m0 + r)*DIN_ + qt*64);
      #pragma unroll
      for (int i=0;i<8;i++){
        uint4 u4 = src[i];
        const unsigned int uu[4] = {u4.x, u4.y, u4.z, u4.w};
        #pragma unroll
        for (int c=0;c<4;c++){
          vals[i*8+c*2]   = bflo(uu[c]);
          vals[i*8+c*2+1] = bfhi(uu[c]);
        }
      }
    } else {
      const float4* src = (const float4*)((const float*)feats + (size_t)(m0 + r)*DIN_ + qt*64);
      #pragma unroll
      for (int i=0;i<16;i++){
        float4 v = src[i];
        vals[i*4+0]=v.x; vals[i*4+1]=v.y; vals[i*4+2]=v.z; vals[i*4+3]=v.w;
      }
    }
    float sum=0.f, sq=0.f;
    #pragma unroll
    for (int i=0;i<64;i++){ sum += vals[i]; sq += vals[i]*vals[i]; }
    sum += __shfl_xor(sum, 1); sum += __shfl_xor(sum, 2);
    sq  += __shfl_xor(sq, 1);  sq  += __shfl_xor(sq, 2);
    const float mean = sum * (1.f/256.f);
    const float var  = sq * (1.f/256.f) - mean*mean;
    const float rstd = rsqrtf(var + 1e-5f);
    #pragma unroll
    for (int i=0;i<8;i++){
      const int kk = qt*64 + i*8;
      unsigned int outp[4];
      #pragma unroll
      for (int c=0;c<4;c++){
        const int k0 = kk + c*2;
        float a = (vals[i*8+c*2]   - mean)*rstd*gf_s[k0]   + bf_s[k0];
        float b = (vals[i*8+c*2+1] - mean)*rstd*gf_s[k0+1] + bf_s[k0+1];
        outp[c] = (unsigned int)f2bf(a) | ((unsigned int)f2bf(b) << 16);
      }
      const int u = ((r>>4)*8 + (kk>>5))*64 + (((kk>>3)&3)<<4) + (r&15);
      ((uint4*)smem)[u] = make_uint4(outp[0],outp[1],outp[2],outp[3]);
    }
    __syncthreads();
    f32x4 acc[4][2];
    #pragma unroll
    for (int mf=0;mf<4;mf++){
      acc[mf][0] = (f32x4){0.f,0.f,0.f,0.f};
      acc[mf][1] = (f32x4){0.f,0.f,0.f,0.f};
    }
    #pragma unroll
    for (int kt=0;kt<8;kt++){
      #pragma unroll
      for (int mf=0;mf<4;mf++){
        bf16x8 a = ((const bf16x8*)smem)[(mf*8+kt)*64 + lane];
        acc[mf][0] = __builtin_amdgcn_mfma_f32_16x16x32_bf16(a, wreg[0][kt], acc[mf][0], 0,0,0);
        acc[mf][1] = __builtin_amdgcn_mfma_f32_16x16x32_bf16(a, wreg[1][kt], acc[mf][1], 0,0,0);
      }
    }
    __syncthreads();
    #pragma unroll
    for (int mf=0;mf<4;mf++){
      #pragma unroll
      for (int nf=0;nf<2;nf++){
        #pragma unroll
        for (int rg=0;rg<4;rg++){
          const int row = mf*16 + ((lane>>4)<<2) + rg;
          const int col = w*32 + nf*16 + (lane&15);
          smem[row*136 + col] = f2bf(acc[mf][nf][rg]);
        }
      }
    }
    __syncthreads();
    #pragma unroll
    for (int it=0; it<4; it++){
      const int idx = it*256 + tid;
      const int row = idx >> 4, cg = idx & 15;
      uint4 val = *(const uint4*)(smem + row*136 + cg*8);
      const int c = cg*8;
      const size_t m = (size_t)(m0 + row);
      if (c < 64) *(uint4*)(Kout + m*64 + c)      = val;
      else        *(uint4*)(Vout + m*64 + (c-64)) = val;
    }
    __syncthreads();
  }
}

// ---------------------------------------------------------------------------
// Persistent iteration kernel, 512 blocks x 256 threads (2 blocks/CU).
// Block (b,g)=(bid>>3, bid&7): attention on tiles t=g and t=g+8 (256 feats
// each, thread-per-feature, 8-deep load ILP), ONE gsync/iter, then REDUNDANT
// per-block update of all 8 slots of b (bitwise identical across the 8 blocks
// sharing b -> next-iteration q needs no barrier). Partials parity-buffered.
// ---------------------------------------------------------------------------
__global__ __launch_bounds__(256, 2) void k_iter(
    const void* __restrict__ slots0,
    const ushort_t* __restrict__ Kmat, const ushort_t* __restrict__ Vmat,
    float* __restrict__ pupd, float* __restrict__ psum, float* __restrict__ pvsum,
    const void* __restrict__ gf,
    const void* __restrict__ Wq, const void* __restrict__ gs, const void* __restrict__ bs,
    const void* __restrict__ W_ih, const void* __restrict__ W_hh,
    const void* __restrict__ b_ih, const void* __restrict__ b_hh,
    const void* __restrict__ gm, const void* __restrict__ bm,
    const void* __restrict__ W1, const void* __restrict__ b1,
    const void* __restrict__ W2, const void* __restrict__ b2,
    unsigned int* bar, void* __restrict__ d_out)
{
  __shared__ __align__(16) char smraw[45056];
  // persistent across phases:
  float*    snl  = (float*)smraw;                 // 8*64*4 = 2048 B : s_n for this b
  float*    at_q = (float*)(smraw + 2048);        // 8*64*4 = 2048 B : scaled q for this b
  // attention overlays (region @4096, 40960 B):
  float*    at_p = (float*)(smraw + 4096);        // 8*256*4 = 8192 B
  ushort_t* at_v = (ushort_t*)(smraw + 12288);    // 256*64*2 = 32768 B
  // update overlays (same region):
  float*    updl = (float*)(smraw + 4096);        // 2048 B
  float*    ml   = (float*)(smraw + 6144);        // 2048 B
  float*    hl   = (float*)(smraw + 8192);        // 8*256*4 = 8192 B

  const int bf  = (*(const unsigned int*)gf == 0x3F803F80u);
  const int tid = threadIdx.x;
  const int bid = blockIdx.x;
  const int b = bid >> 3, g = bid & 7;
  const int d = tid & 63, s = tid >> 6;       // thread owns slot pairs (s,d),(s+4,d)
  float sn0 = 0.f, sn1 = 0.f;                 // s_n for pairs, carried across iterations

  // ---- prologue: s_n = LN(slots0[b]), q0 = s_n @ Wq^T * scale (per-block local) ----
  {
    const float x0 = ldf(slots0, (b*S_+s  )*64 + d, bf);
    const float x1 = ldf(slots0, (b*S_+s+4)*64 + d, bf);
    float su0=x0, sg0=x0*x0, su1=x1, sg1=x1*x1;
    #pragma unroll
    for (int o=1;o<64;o<<=1){
      su0 += __shfl_xor(su0,o); sg0 += __shfl_xor(sg0,o);
      su1 += __shfl_xor(su1,o); sg1 += __shfl_xor(sg1,o);
    }
    const float m0 = su0*(1.f/64.f), v0 = sg0*(1.f/64.f)-m0*m0, r0 = rsqrtf(v0+1e-5f);
    const float m1 = su1*(1.f/64.f), v1 = sg1*(1.f/64.f)-m1*m1, r1 = rsqrtf(v1+1e-5f);
    const float gsv = ldf(gs,d,bf), bsv = ldf(bs,d,bf);
    sn0 = (x0-m0)*r0*gsv + bsv;
    sn1 = (x1-m1)*r1*gsv + bsv;
    snl[s*64+d] = sn0; snl[(s+4)*64+d] = sn1;   // same-wave write->read below
    float q0, q1;
    dot2(Wq, (size_t)d*64, snl + s*64, snl + (s+4)*64, 8, bf, q0, q1);
    at_q[s*64+d] = q0*0.125f; at_q[(s+4)*64+d] = q1*0.125f;
  }

  for (int it=0; it<3; it++){
    const int pb = it & 1;                      // parity buffer select
    // ==================== attention: tiles t=g, t=g+8 ====================
    float a0=0.f, a1=0.f, vs=0.f, ps_acc=0.f;
    #pragma unroll
    for (int half=0; half<2; half++){
      const int f0 = (g + half*8)*FT_;
      __syncthreads();   // orders prologue/update writes (at_q, snl) + overlay reuse
      {
        const uint4* vsrc = (const uint4*)(Vmat + ((size_t)b*F_ + f0)*64);
        #pragma unroll
        for (int i=0;i<8;i++) ((uint4*)at_v)[i*256+tid] = vsrc[i*256+tid];
      }
      __syncthreads();
      // phase 1: thread-per-feature (8 K-loads in flight), softmax over slots
      {
        const int f = tid;
        const uint4* kr = (const uint4*)(Kmat + ((size_t)b*F_ + f0 + f)*64);
        float dots[8];
        #pragma unroll
        for (int ss=0;ss<8;ss++) dots[ss]=0.f;
        #pragma unroll
        for (int c=0;c<8;c++){
          uint4 u = kr[c];
          const float v0=bflo(u.x), v1=bfhi(u.x), v2=bflo(u.y), v3=bfhi(u.y);
          const float v4=bflo(u.z), v5=bfhi(u.z), v6=bflo(u.w), v7=bfhi(u.w);
          const int k0 = c*8;
          #pragma unroll
          for (int ss=0;ss<8;ss++){
            const float* qs = &at_q[ss*64+k0];
            dots[ss] += v0*qs[0]+v1*qs[1]+v2*qs[2]+v3*qs[3]+v4*qs[4]+v5*qs[5]+v6*qs[6]+v7*qs[7];
          }
        }
        float mx = dots[0];
        #pragma unroll
        for (int ss=1;ss<8;ss++) mx = fmaxf(mx, dots[ss]);
        float es[8]; float tot=0.f;
        #pragma unroll
        for (int ss=0;ss<8;ss++){ es[ss] = __expf(dots[ss]-mx); tot += es[ss]; }
        const float inv = 1.f/tot;
        #pragma unroll
        for (int ss=0;ss<8;ss++){
          const float p = es[ss]*inv;
          at_p[ss*FT_ + f] = p;
          if (it==2){
            const size_t off = ((size_t)(b*S_+ss))*F_ + f0 + f;
            if (bf) ((ushort_t*)d_out + B_*S_*D_)[off] = f2bf(p);
            else    ((float*)d_out    + B_*S_*D_)[off] = p;
          }
        }
      }
      __syncthreads();
      // phase 2: accumulate partial updates across both tiles
      {
        const int sg = s;
        #pragma unroll 4
        for (int f=0; f<FT_; f++){
          const float v = bf2f(at_v[f*64 + d]);
          a0 += at_p[sg*FT_ + f] * v;
          a1 += at_p[(sg+4)*FT_ + f] * v;
          if (sg==0) vs += v;
        }
      }
      // phase 2b: per-slot p sums (at_p read-only until next barrier)
      if (tid < 64){
        const int ss = tid >> 3, part = tid & 7;
        float ssum = 0.f;
        #pragma unroll
        for (int j=0;j<32;j++) ssum += at_p[ss*FT_ + part*32 + j];
        ssum += __shfl_xor(ssum,1); ssum += __shfl_xor(ssum,2); ssum += __shfl_xor(ssum,4);
        ps_acc += ssum;
      }
    }
    // write partials (parity buffer pb); completed by gsync's pre-barrier drain
    {
      float* pu = pupd  + pb*262144;   // [512][8][64] floats
      float* pv = pvsum + pb*32768;    // [512][64]
      float* pp = psum  + pb*4096;     // [512][8]
      agstore(&pu[((size_t)bid*S_ + s  )*64 + d], a0);
      agstore(&pu[((size_t)bid*S_ + s+4)*64 + d], a1);
      if (s==0) agstore(&pv[(size_t)bid*64 + d], vs);
      if (tid < 64 && (tid&7)==0) agstore(&pp[bid*S_ + (tid>>3)], ps_acc);
    }
    gsync(bar);

    // ==================== redundant per-block update of batch b ====================
    if (it==2 && g!=0){
      // only g==0 blocks must produce the slot outputs; others are done
      // (attn outputs were written during phase 1)
      return;
    }
    {
      const float* pu = pupd  + pb*262144;
      const float* pv = pvsum + pb*32768;
      const float* pp = psum  + pb*4096;
      float raw0=0.f, raw1=0.f, vsum=0.f, sp0=0.f, sp1=0.f;
      #pragma unroll
      for (int j=0;j<8;j++){
        const int bg = b*8 + j;
        raw0 += agload(&pu[((size_t)bg*S_ + s  )*64 + d]);
        raw1 += agload(&pu[((size_t)bg*S_ + s+4)*64 + d]);
        vsum += agload(&pv[(size_t)bg*64 + d]);
        sp0  += agload(&pp[bg*S_ + s]);
        sp1  += agload(&pp[bg*S_ + s+4]);
      }
      const float upd0 = (raw0 + 1e-8f*vsum) / (sp0 + 1e-8f*(float)F_);
      const float upd1 = (raw1 + 1e-8f*vsum) / (sp1 + 1e-8f*(float)F_);
      updl[s*64+d] = upd0; updl[(s+4)*64+d] = upd1;   // same-wave write->read in GRU dots
      // GRU gates (per-gate dot order identical to prior rounds)
      float gi_r0,gi_r1, gi_z0,gi_z1, gi_n0,gi_n1;
      float gh_r0,gh_r1, gh_z0,gh_z1, gh_n0,gh_n1;
      dot2(W_ih, (size_t)(d)*64,     updl+s*64, updl+(s+4)*64, 8, bf, gi_r0, gi_r1);
      dot2(W_ih, (size_t)(64+d)*64,  updl+s*64, updl+(s+4)*64, 8, bf, gi_z0, gi_z1);
      dot2(W_ih, (size_t)(128+d)*64, updl+s*64, updl+(s+4)*64, 8, bf, gi_n0, gi_n1);
      dot2(W_hh, (size_t)(d)*64,     snl+s*64,  snl+(s+4)*64,  8, bf, gh_r0, gh_r1);
      dot2(W_hh, (size_t)(64+d)*64,  snl+s*64,  snl+(s+4)*64,  8, bf, gh_z0, gh_z1);
      dot2(W_hh, (size_t)(128+d)*64, snl+s*64,  snl+(s+4)*64,  8, bf, gh_n0, gh_n1);
      const float bir = ldf(b_ih,d,bf), biz = ldf(b_ih,64+d,bf), bin = ldf(b_ih,128+d,bf);
      const float bhr = ldf(b_hh,d,bf), bhz = ldf(b_hh,64+d,bf), bhn = ldf(b_hh,128+d,bf);
      gi_r0+=bir; gi_r1+=bir; gi_z0+=biz; gi_z1+=biz; gi_n0+=bin; gi_n1+=bin;
      gh_r0+=bhr; gh_r1+=bhr; gh_z0+=bhz; gh_z1+=bhz; gh_n0+=bhn; gh_n1+=bhn;
      const float rr0 = 1.f/(1.f+__expf(-(gi_r0+gh_r0)));
      const float rr1 = 1.f/(1.f+__expf(-(gi_r1+gh_r1)));
      const float zz0 = 1.f/(1.f+__expf(-(gi_z0+gh_z0)));
      const float zz1 = 1.f/(1.f+__expf(-(gi_z1+gh_z1)));
      float na0 = gi_n0 + rr0*gh_n0; na0 = fminf(fmaxf(na0,-15.f),15.f);
      float na1 = gi_n1 + rr1*gh_n1; na1 = fminf(fmaxf(na1,-15.f),15.f);
      const float en0 = __expf(2.f*na0), nn0 = (en0-1.f)/(en0+1.f);
      const float en1 = __expf(2.f*na1), nn1 = (en1-1.f)/(en1+1.f);
      const float newv0 = (1.f-zz0)*nn0 + zz0*sn0;
      const float newv1 = (1.f-zz1)*nn1 + zz1*sn1;
      // LN per slot (wave-wide shfl) for MLP input
      float su0=newv0, sg0=newv0*newv0, su1=newv1, sg1=newv1*newv1;
      #pragma unroll
      for (int o=1;o<64;o<<=1){
        su0 += __shfl_xor(su0,o); sg0 += __shfl_xor(sg0,o);
        su1 += __shfl_xor(su1,o); sg1 += __shfl_xor(sg1,o);
      }
      const float m0 = su0*(1.f/64.f), v0 = sg0*(1.f/64.f)-m0*m0, rs0 = rsqrtf(v0+1e-5f);
      const float m1 = su1*(1.f/64.f), v1 = sg1*(1.f/64.f)-m1*m1, rs1 = rsqrtf(v1+1e-5f);
      const float gmv = ldf(gm,d,bf), bmv = ldf(bm,d,bf);
      ml[s*64+d]     = (newv0-m0)*rs0*gmv + bmv;
      ml[(s+4)*64+d] = (newv1-m1)*rs1*gmv + bmv;
      __syncthreads();    // ml complete (cross-slot MLP1)
      // MLP layer 1: 2048 outputs over 256 threads (c = slot)
      #pragma unroll
      for (int c=0;c<8;c++)
        hl[c*256+tid] = fmaxf(dotN(W1, (size_t)tid*64, ml + c*64, 8, bf) + ldf(b1,tid,bf), 0.f);
      __syncthreads();    // hl complete
      // MLP layer 2 + residual
      float ac0, ac1;
      dot2(W2, (size_t)d*256, hl + s*256, hl + (s+4)*256, 32, bf, ac0, ac1);
      const float b2v = ldf(b2,d,bf);
      const float outv0 = newv0 + (ac0 + b2v);
      const float outv1 = newv1 + (ac1 + b2v);
      if (it == 2){
        // g==0 only (others returned above)
        if (bf){
          ((ushort_t*)d_out)[(b*S_+s  )*64+d] = f2bf(outv0);
          ((ushort_t*)d_out)[(b*S_+s+4)*64+d] = f2bf(outv1);
        } else {
          ((float*)d_out)[(b*S_+s  )*64+d] = outv0;
          ((float*)d_out)[(b*S_+s+4)*64+d] = outv1;
        }
      } else {
        // next-iteration s_n and q (block-local, identical across the 8 blocks of b)
        float ts0=outv0, tq0=outv0*outv0, ts1=outv1, tq1=outv1*outv1;
        #pragma unroll
        for (int o=1;o<64;o<<=1){
          ts0 += __shfl_xor(ts0,o); tq0 += __shfl_xor(tq0,o);
          ts1 += __shfl_xor(ts1,o); tq1 += __shfl_xor(tq1,o);
        }
        const float mm0 = ts0*(1.f/64.f), vv0 = tq0*(1.f/64.f)-mm0*mm0, rr0b = rsqrtf(vv0+1e-5f);
        const float mm1 = ts1*(1.f/64.f), vv1 = tq1*(1.f/64.f)-mm1*mm1, rr1b = rsqrtf(vv1+1e-5f);
        const float gsv = ldf(gs,d,bf), bsv = ldf(bs,d,bf);
        sn0 = (outv0-mm0)*rr0b*gsv + bsv;
        sn1 = (outv1-mm1)*rr1b*gsv + bsv;
        snl[s*64+d] = sn0; snl[(s+4)*64+d] = sn1;   // same-wave write->read
        float q0, q1;
        dot2(Wq, (size_t)d*64, snl + s*64, snl + (s+4)*64, 8, bf, q0, q1);
        at_q[s*64+d] = q0*0.125f; at_q[(s+4)*64+d] = q1*0.125f;
        // next iteration's first __syncthreads orders at_q/snl for all waves
      }
    }
  }
}

// ---------------------------------------------------------------------------
extern "C" void kernel_launch(void* const* d_in, const int* in_sizes, int n_in,
                              void* d_out, int out_size, void* d_ws, size_t ws_size,
                              hipStream_t stream)
{
  const void* slots0 = d_in[0];
  const void* feats  = d_in[1];
  const void* gf     = d_in[2];
  const void* bfp    = d_in[3];
  const void* Wk     = d_in[4];
  const void* Wv     = d_in[5];
  const void* Wq     = d_in[6];
  const void* gs     = d_in[7];
  const void* bs     = d_in[8];
  const void* W_ih   = d_in[9];
  const void* W_hh   = d_in[10];
  const void* b_ih   = d_in[11];
  const void* b_hh   = d_in[12];
  const void* gm     = d_in[13];
  const void* bm     = d_in[14];
  const void* W1     = d_in[15];
  const void* b1     = d_in[16];
  const void* W2     = d_in[17];
  const void* b2     = d_in[18];

  // Workspace layout — identical footprint to round-0's proven layout.
  const size_t NEED = 69894148;
  if (ws_size < NEED){
    k_sentinel<<<dim3(8192), dim3(256), 0, stream>>>((ushort_t*)d_out,
                                                     (ushort_t*)d_out + B_*S_*D_,
                                                     (float)(ws_size >> 20));
    return;
  }

  char* ws = (char*)d_ws;
  ushort_t* Kmat   = (ushort_t*)(ws);                // 33,554,432 B
  ushort_t* Vmat   = (ushort_t*)(ws + 33554432);     // 33,554,432 B
  float* pupd      = (float*)(ws + 67108864);        //  2,097,152 B (2x parity 1 MB)
  float* pvsum     = (float*)(ws + 69206016);        //    262,144 B (2x parity 128 KB)
  unsigned int* bar= (unsigned int*)(ws + 69730304); //         64 B
  float* psum      = (float*)(ws + 69861376);        //     32,768 B (2x parity 16 KB)

  k_lnproj<<<dim3(2048), dim3(256), 0, stream>>>(feats, gf, bfp, Wk, Wv, Kmat, Vmat, bar);
  k_iter<<<dim3(NB2_), dim3(256), 0, stream>>>(slots0, Kmat, Vmat, pupd, psum, pvsum,
                                               gf, Wq, gs, bs, W_ih, W_hh, b_ih, b_hh,
                                               gm, bm, W1, b1, W2, b2, bar, d_out);
}

// Round 5
// 559.270 us; speedup vs baseline: 1.6049x; 1.6049x over previous
//
#include <hip/hip_runtime.h>

#define B_ 64
#define S_ 8
#define F_ 4096
#define DIN_ 256
#define D_ 64
#define H_ 256
#define T_ 16      // feature tiles per batch in attention
#define FT_ 256    // features per attention tile

typedef unsigned short ushort_t;
typedef __attribute__((ext_vector_type(8))) short bf16x8;
typedef __attribute__((ext_vector_type(4))) float f32x4;

__device__ __forceinline__ float bflo(unsigned int u){ union{unsigned int i; float f;} v; v.i = u<<16; return v.f; }
__device__ __forceinline__ float bfhi(unsigned int u){ union{unsigned int i; float f;} v; v.i = u & 0xffff0000u; return v.f; }
__device__ __forceinline__ float bf2f(ushort_t s){ union{unsigned int i; float f;} v; v.i = ((unsigned int)s)<<16; return v.f; }
__device__ __forceinline__ ushort_t f2bf(float f){ union{float f; unsigned int i;} v; v.f = f; unsigned int u = v.i; u += 0x7fffu + ((u>>16)&1u); return (ushort_t)(u>>16); }

#define DOT8(u, xp, acc) \
  acc += bflo((u).x)*(xp)[0]+bfhi((u).x)*(xp)[1]+bflo((u).y)*(xp)[2]+bfhi((u).y)*(xp)[3] \
       + bflo((u).z)*(xp)[4]+bfhi((u).z)*(xp)[5]+bflo((u).w)*(xp)[6]+bfhi((u).w)*(xp)[7]

// dtype-dual scalar load of logical fp32 element i
__device__ __forceinline__ float ldf(const void* p, int i, int bf){
  return bf ? bf2f(((const ushort_t*)p)[i]) : ((const float*)p)[i];
}

// dtype-dual dot of row W[base..base+n8*8) with x[0..n8*8); base multiple of 8
__device__ __forceinline__ float dotN(const void* W, size_t base, const float* x, int n8, int bf){
  float acc = 0.f;
  if (bf){
    const uint4* wr = (const uint4*)((const ushort_t*)W + base);
    #pragma unroll
    for (int c=0;c<n8;c++){ uint4 u = wr[c]; const float* xp = x + c*8; DOT8(u, xp, acc); }
  } else {
    const float4* wr = (const float4*)((const float*)W + base);
    #pragma unroll
    for (int c=0;c<n8*2;c++){
      float4 wv = wr[c]; const float* xp = x + c*4;
      acc += wv.x*xp[0]+wv.y*xp[1]+wv.z*xp[2]+wv.w*xp[3];
    }
  }
  return acc;
}

// ---------------------------------------------------------------------------
__global__ __launch_bounds__(256) void k_sentinel(ushort_t* __restrict__ out_slots,
                                                  ushort_t* __restrict__ out_attn, float val)
{
  const int i = blockIdx.x*256 + threadIdx.x;
  if (i < B_*S_*D_) out_slots[i] = f2bf(val);
  for (int j = i; j < B_*S_*F_; j += gridDim.x*256) out_attn[j] = 0;
}

// ---------------------------------------------------------------------------
// Kernel 1 (round-0 proven, 2048 blocks): LN(features) + [K|V] proj via MFMA.
// ---------------------------------------------------------------------------
__global__ __launch_bounds__(256) void k_lnproj(
    const void* __restrict__ feats, const void* __restrict__ gf, const void* __restrict__ bfp,
    const void* __restrict__ Wk, const void* __restrict__ Wv,
    ushort_t* __restrict__ Kout, ushort_t* __restrict__ Vout)
{
  __shared__ ushort_t smem[16384];
  __shared__ float gf_s[256], bf_s[256];
  const int bf = (*(const unsigned int*)gf == 0x3F803F80u);
  const int tid = threadIdx.x;
  const int lane = tid & 63, w = tid >> 6;
  if (tid < 256){ gf_s[tid] = ldf(gf, tid, bf); bf_s[tid] = ldf(bfp, tid, bf); }
  bf16x8 wreg[2][8];
  #pragma unroll
  for (int nf=0; nf<2; nf++){
    const int n = w*32 + nf*16 + (lane&15);
    if (bf){
      const ushort_t* wrow = (n < 64) ? ((const ushort_t*)Wk + n*DIN_)
                                      : ((const ushort_t*)Wv + (n-64)*DIN_);
      #pragma unroll
      for (int kt=0; kt<8; kt++)
        wreg[nf][kt] = *(const bf16x8*)(wrow + kt*32 + ((lane>>4)<<3));
    } else {
      const float* wrow = (n < 64) ? ((const float*)Wk + n*DIN_)
                                   : ((const float*)Wv + (n-64)*DIN_);
      #pragma unroll
      for (int kt=0; kt<8; kt++){
        const float* wp = wrow + kt*32 + ((lane>>4)<<3);
        bf16x8 t;
        #pragma unroll
        for (int j=0;j<8;j++) t[j] = (short)f2bf(wp[j]);
        wreg[nf][kt] = t;
      }
    }
  }
  __syncthreads();
  const int r = tid >> 2, qt = tid & 3;
  for (int tile = blockIdx.x; tile < 4096; tile += gridDim.x){
    const int m0 = tile*64;
    float vals[64];
    if (bf){
      const uint4* src = (const uint4*)((const ushort_t*)feats + (size_t)(m0 + r)*DIN_ + qt*64);
      #pragma unroll
      for (int i=0;i<8;i++){
        uint4 u4 = src[i];
        const unsigned int uu[4] = {u4.x, u4.y, u4.z, u4.w};
        #pragma unroll
        for (int c=0;c<4;c++){
          vals[i*8+c*2]   = bflo(uu[c]);
          vals[i*8+c*2+1] = bfhi(uu[c]);
        }
      }
    } else {
      const float4* src = (const float4*)((const float*)feats + (size_t)(m0 + r)*DIN_ + qt*64);
      #pragma unroll
      for (int i=0;i<16;i++){
        float4 v = src[i];
        vals[i*4+0]=v.x; vals[i*4+1]=v.y; vals[i*4+2]=v.z; vals[i*4+3]=v.w;
      }
    }
    float sum=0.f, sq=0.f;
    #pragma unroll
    for (int i=0;i<64;i++){ sum += vals[i]; sq += vals[i]*vals[i]; }
    sum += __shfl_xor(sum, 1); sum += __shfl_xor(sum, 2);
    sq  += __shfl_xor(sq, 1);  sq  += __shfl_xor(sq, 2);
    const float mean = sum * (1.f/256.f);
    const float var  = sq * (1.f/256.f) - mean*mean;
    const float rstd = rsqrtf(var + 1e-5f);
    #pragma unroll
    for (int i=0;i<8;i++){
      const int kk = qt*64 + i*8;
      unsigned int outp[4];
      #pragma unroll
      for (int c=0;c<4;c++){
        const int k0 = kk + c*2;
        float a = (vals[i*8+c*2]   - mean)*rstd*gf_s[k0]   + bf_s[k0];
        float b = (vals[i*8+c*2+1] - mean)*rstd*gf_s[k0+1] + bf_s[k0+1];
        outp[c] = (unsigned int)f2bf(a) | ((unsigned int)f2bf(b) << 16);
      }
      const int u = ((r>>4)*8 + (kk>>5))*64 + (((kk>>3)&3)<<4) + (r&15);
      ((uint4*)smem)[u] = make_uint4(outp[0],outp[1],outp[2],outp[3]);
    }
    __syncthreads();
    f32x4 acc[4][2];
    #pragma unroll
    for (int mf=0;mf<4;mf++){
      acc[mf][0] = (f32x4){0.f,0.f,0.f,0.f};
      acc[mf][1] = (f32x4){0.f,0.f,0.f,0.f};
    }
    #pragma unroll
    for (int kt=0;kt<8;kt++){
      #pragma unroll
      for (int mf=0;mf<4;mf++){
        bf16x8 a = ((const bf16x8*)smem)[(mf*8+kt)*64 + lane];
        acc[mf][0] = __builtin_amdgcn_mfma_f32_16x16x32_bf16(a, wreg[0][kt], acc[mf][0], 0,0,0);
        acc[mf][1] = __builtin_amdgcn_mfma_f32_16x16x32_bf16(a, wreg[1][kt], acc[mf][1], 0,0,0);
      }
    }
    __syncthreads();
    #pragma unroll
    for (int mf=0;mf<4;mf++){
      #pragma unroll
      for (int nf=0;nf<2;nf++){
        #pragma unroll
        for (int rg=0;rg<4;rg++){
          const int row = mf*16 + ((lane>>4)<<2) + rg;
          const int col = w*32 + nf*16 + (lane&15);
          smem[row*136 + col] = f2bf(acc[mf][nf][rg]);
        }
      }
    }
    __syncthreads();
    #pragma unroll
    for (int it=0; it<4; it++){
      const int idx = it*256 + tid;
      const int row = idx >> 4, cg = idx & 15;
      uint4 val = *(const uint4*)(smem + row*136 + cg*8);
      const int c = cg*8;
      const size_t m = (size_t)(m0 + row);
      if (c < 64) *(uint4*)(Kout + m*64 + c)      = val;
      else        *(uint4*)(Vout + m*64 + (c-64)) = val;
    }
    __syncthreads();
  }
}

// ---------------------------------------------------------------------------
// q0: s_n = LN(slots0), q = scale * s_n @ Wq^T. One block per (b,s). (round-0 proven)
// ---------------------------------------------------------------------------
__global__ __launch_bounds__(64) void k_q0(
    const void* __restrict__ slots_in,
    const void* __restrict__ gs, const void* __restrict__ bs,
    const void* __restrict__ Wq, const void* __restrict__ gf,
    float* __restrict__ sn_out, float* __restrict__ q_out)
{
  __shared__ float snl[64];
  const int bf = (*(const unsigned int*)gf == 0x3F803F80u);
  const int bs_id = blockIdx.x;
  const int d = threadIdx.x;
  const int idx = bs_id*64 + d;
  const float x = ldf(slots_in, idx, bf);
  float sum = x, sq = x*x;
  #pragma unroll
  for (int o=1;o<64;o<<=1){ sum += __shfl_xor(sum,o); sq += __shfl_xor(sq,o); }
  const float mean = sum*(1.f/64.f);
  const float var  = sq*(1.f/64.f) - mean*mean;
  const float rstd = rsqrtf(var + 1e-5f);
  const float sn = (x-mean)*rstd*ldf(gs,d,bf) + ldf(bs,d,bf);
  sn_out[idx] = sn;
  snl[d] = sn;
  __syncthreads();
  q_out[idx] = dotN(Wq, (size_t)d*64, snl, 8, bf) * 0.125f;
}

// ---------------------------------------------------------------------------
// Attention (round-0 proven structure): per (t,b) block; dots -> per-feature
// softmax over 8 slots -> partial sums. Phase 2 uses float4 p-loads (same
// per-accumulator add order as the scalar version).
// ---------------------------------------------------------------------------
__global__ __launch_bounds__(256) void k_attn(
    const ushort_t* __restrict__ Kmat, const ushort_t* __restrict__ Vmat,
    const float* __restrict__ qv, const void* __restrict__ gf,
    float* __restrict__ p_upd, float* __restrict__ p_sum, float* __restrict__ p_vsum,
    void* __restrict__ d_out, int write_attn)
{
  __shared__ float q_s[512];
  __shared__ float p_lds[8*FT_];
  __shared__ ushort_t V_lds[FT_*64];
  const int bf = (*(const unsigned int*)gf == 0x3F803F80u);
  const int t = blockIdx.x, b = blockIdx.y;
  const int tid = threadIdx.x;
  const int f0 = t*FT_;
  q_s[tid]     = qv[b*512 + tid];
  q_s[tid+256] = qv[b*512 + 256 + tid];
  {
    const uint4* vsrc = (const uint4*)(Vmat + ((size_t)b*F_ + f0)*64);
    #pragma unroll
    for (int i=0;i<8;i++) ((uint4*)V_lds)[i*256+tid] = vsrc[i*256+tid];
  }
  __syncthreads();
  // phase 1: one thread per feature — 8 dots, softmax over slots
  {
    const int f = tid;
    const uint4* kr = (const uint4*)(Kmat + ((size_t)b*F_ + f0 + f)*64);
    float dots[8];
    #pragma unroll
    for (int s=0;s<8;s++) dots[s]=0.f;
    #pragma unroll
    for (int c=0;c<8;c++){
      uint4 u = kr[c];
      const float v0=bflo(u.x), v1=bfhi(u.x), v2=bflo(u.y), v3=bfhi(u.y);
      const float v4=bflo(u.z), v5=bfhi(u.z), v6=bflo(u.w), v7=bfhi(u.w);
      const int k0 = c*8;
      #pragma unroll
      for (int s=0;s<8;s++){
        const float* qs = &q_s[s*64+k0];
        dots[s] += v0*qs[0]+v1*qs[1]+v2*qs[2]+v3*qs[3]+v4*qs[4]+v5*qs[5]+v6*qs[6]+v7*qs[7];
      }
    }
    float mx = dots[0];
    #pragma unroll
    for (int s=1;s<8;s++) mx = fmaxf(mx, dots[s]);
    float es[8]; float tot=0.f;
    #pragma unroll
    for (int s=0;s<8;s++){ es[s] = __expf(dots[s]-mx); tot += es[s]; }
    const float inv = 1.f/tot;
    #pragma unroll
    for (int s=0;s<8;s++){
      const float p = es[s]*inv;
      p_lds[s*FT_ + f] = p;
      if (write_attn){
        const size_t off = ((size_t)(b*S_+s))*F_ + f0 + f;
        if (bf) ((ushort_t*)d_out + B_*S_*D_)[off] = f2bf(p);
        else    ((float*)d_out    + B_*S_*D_)[off] = p;
      }
    }
  }
  __syncthreads();
  // phase 2: partial updates — thread (sg,d) handles slots sg and sg+4.
  // float4 p-loads; per-accumulator add order identical to the scalar loop.
  {
    const int d = tid & 63, sg = tid >> 6;
    float a0=0.f, a1=0.f, vs=0.f;
    for (int f4=0; f4<FT_/4; f4++){
      const float4 p0 = *(const float4*)&p_lds[sg*FT_ + f4*4];
      const float4 p1 = *(const float4*)&p_lds[(sg+4)*FT_ + f4*4];
      const float v0 = bf2f(V_lds[(f4*4+0)*64 + d]);
      const float v1 = bf2f(V_lds[(f4*4+1)*64 + d]);
      const float v2 = bf2f(V_lds[(f4*4+2)*64 + d]);
      const float v3 = bf2f(V_lds[(f4*4+3)*64 + d]);
      a0 += p0.x*v0; a0 += p0.y*v1; a0 += p0.z*v2; a0 += p0.w*v3;
      a1 += p1.x*v0; a1 += p1.y*v1; a1 += p1.z*v2; a1 += p1.w*v3;
      if (sg==0){ vs += v0; vs += v1; vs += v2; vs += v3; }
    }
    float* dst = p_upd + (((size_t)b*T_ + t)*S_)*64;
    dst[sg*64 + d]     = a0;
    dst[(sg+4)*64 + d] = a1;
    if (sg==0) p_vsum[((size_t)b*T_ + t)*64 + d] = vs;
  }
  // phase 2b: per-slot p sums (wave 0; p_lds read-only since last barrier)
  if (tid < 64){
    const int s = tid >> 3, part = tid & 7;
    float ssum = 0.f;
    #pragma unroll
    for (int j=0;j<32;j++) ssum += p_lds[s*FT_ + part*32 + j];
    ssum += __shfl_xor(ssum,1); ssum += __shfl_xor(ssum,2); ssum += __shfl_xor(ssum,4);
    if (part==0) p_sum[((size_t)b*T_ + t)*S_ + s] = ssum;
  }
}

// ---------------------------------------------------------------------------
// Update (wave-parallel, 256 threads, proven in rounds 2-3): reduce partials
// -> exact attn normalization -> GRU -> LN -> MLP residual. Also emits the
// NEXT iteration's s_n and q (replaces k_q). One block per (b,s).
// ---------------------------------------------------------------------------
__global__ __launch_bounds__(256) void k_upd(
    const float* __restrict__ p_upd, const float* __restrict__ p_sum, const float* __restrict__ p_vsum,
    float* __restrict__ snbuf, float* __restrict__ qbuf,
    const void* __restrict__ gf,
    const void* __restrict__ Wq, const void* __restrict__ gs, const void* __restrict__ bs,
    const void* __restrict__ W_ih, const void* __restrict__ W_hh,
    const void* __restrict__ b_ih, const void* __restrict__ b_hh,
    const void* __restrict__ gm, const void* __restrict__ bm,
    const void* __restrict__ W1, const void* __restrict__ b1,
    const void* __restrict__ W2, const void* __restrict__ b2,
    void* __restrict__ d_out, int write_out)
{
  __shared__ float red_raw[256], red_vs[256], red_sp[4];
  __shared__ float updl[64], snl[64], g_gi[192], g_gh[192], nv[64], ml[64], hl[256], red2[256];
  const int bf = (*(const unsigned int*)gf == 0x3F803F80u);
  const int bs_id = blockIdx.x;        // b*8+s
  const int b = bs_id >> 3, s = bs_id & 7;
  const int tid = threadIdx.x;
  const int d = tid & 63, w = tid >> 6;
  // wave-parallel t-reduction (order proven in rounds 2-3)
  float raw_p=0.f, vs_p=0.f, sp_p=0.f;
  #pragma unroll
  for (int tt=w; tt<T_; tt+=4){
    raw_p += p_upd[(((size_t)b*T_ + tt)*S_ + s)*64 + d];
    vs_p  += p_vsum[((size_t)b*T_ + tt)*64 + d];
    sp_p  += p_sum[((size_t)b*T_ + tt)*S_ + s];
  }
  red_raw[w*64+d]=raw_p; red_vs[w*64+d]=vs_p; if (d==0) red_sp[w]=sp_p;
  __syncthreads();
  float snv = 0.f;
  if (tid < 64){
    const float raw  = red_raw[d]+red_raw[64+d]+red_raw[128+d]+red_raw[192+d];
    const float vsum = red_vs[d]+red_vs[64+d]+red_vs[128+d]+red_vs[192+d];
    const float sp   = red_sp[0]+red_sp[1]+red_sp[2]+red_sp[3];
    updl[d] = (raw + 1e-8f*vsum) / (sp + 1e-8f*(float)F_);
    snv = snbuf[bs_id*64 + d];
    snl[d] = snv;
  }
  __syncthreads();
  // one GRU gate-row set per wave (waves 0..2); per-gate dot order unchanged
  if (w < 3){
    g_gi[w*64+d] = dotN(W_ih, (size_t)(w*64+d)*64, updl, 8, bf) + ldf(b_ih, w*64+d, bf);
    g_gh[w*64+d] = dotN(W_hh, (size_t)(w*64+d)*64, snl,  8, bf) + ldf(b_hh, w*64+d, bf);
  }
  __syncthreads();
  if (tid < 64){
    const float rr = 1.f/(1.f+__expf(-(g_gi[d]+g_gh[d])));
    const float zz = 1.f/(1.f+__expf(-(g_gi[64+d]+g_gh[64+d])));
    float narg = g_gi[128+d] + rr*g_gh[128+d];
    narg = fminf(fmaxf(narg, -15.f), 15.f);
    const float en = __expf(2.f*narg);
    const float nn = (en-1.f)/(en+1.f);
    const float newv = (1.f-zz)*nn + zz*snv;
    nv[d] = newv;
    float sum=newv, sq=newv*newv;
    #pragma unroll
    for (int o=1;o<64;o<<=1){ sum += __shfl_xor(sum,o); sq += __shfl_xor(sq,o); }
    const float mean = sum*(1.f/64.f);
    const float var  = sq*(1.f/64.f)-mean*mean;
    const float rstd = rsqrtf(var+1e-5f);
    ml[d] = (newv-mean)*rstd*ldf(gm,d,bf) + ldf(bm,d,bf);
  }
  __syncthreads();
  // MLP layer 1: 256 outputs over 256 threads
  hl[tid] = fmaxf(dotN(W1, (size_t)tid*64, ml, 8, bf) + ldf(b1, tid, bf), 0.f);
  __syncthreads();
  // MLP layer 2: quarter-dots per wave
  red2[w*64+d] = dotN(W2, (size_t)d*256 + w*64, hl + w*64, 8, bf);
  __syncthreads();
  if (tid < 64){
    const float acc2 = red2[d]+red2[64+d]+red2[128+d]+red2[192+d] + ldf(b2, d, bf);
    const float outv = nv[d] + acc2;
    if (write_out){
      if (bf) ((ushort_t*)d_out)[bs_id*64+d] = f2bf(outv);
      else    ((float*)d_out)[bs_id*64+d]    = outv;
    } else {
      // next iteration: s_n = LN(slots, gs, bs), q = scale * s_n @ Wq^T
      float s2=outv, q2=outv*outv;
      #pragma unroll
      for (int o=1;o<64;o<<=1){ s2 += __shfl_xor(s2,o); q2 += __shfl_xor(q2,o); }
      const float mean2 = s2*(1.f/64.f);
      const float var2  = q2*(1.f/64.f)-mean2*mean2;
      const float rstd2 = rsqrtf(var2+1e-5f);
      const float snn = (outv-mean2)*rstd2*ldf(gs,d,bf) + ldf(bs,d,bf);
      snbuf[bs_id*64+d] = snn;
      snl[d] = snn;                      // same-wave LDS RAW (proven pattern)
      qbuf[bs_id*64+d] = dotN(Wq, (size_t)d*64, snl, 8, bf) * 0.125f;
    }
  }
}

// ---------------------------------------------------------------------------
extern "C" void kernel_launch(void* const* d_in, const int* in_sizes, int n_in,
                              void* d_out, int out_size, void* d_ws, size_t ws_size,
                              hipStream_t stream)
{
  const void* slots0 = d_in[0];
  const void* feats  = d_in[1];
  const void* gf     = d_in[2];
  const void* bfp    = d_in[3];
  const void* Wk     = d_in[4];
  const void* Wv     = d_in[5];
  const void* Wq     = d_in[6];
  const void* gs     = d_in[7];
  const void* bs     = d_in[8];
  const void* W_ih   = d_in[9];
  const void* W_hh   = d_in[10];
  const void* b_ih   = d_in[11];
  const void* b_hh   = d_in[12];
  const void* gm     = d_in[13];
  const void* bm     = d_in[14];
  const void* W1     = d_in[15];
  const void* b1     = d_in[16];
  const void* W2     = d_in[17];
  const void* b2     = d_in[18];

  // Workspace layout — identical footprint to round-0's proven layout.
  const size_t NEED = 69894148;
  if (ws_size < NEED){
    k_sentinel<<<dim3(8192), dim3(256), 0, stream>>>((ushort_t*)d_out,
                                                     (ushort_t*)d_out + B_*S_*D_,
                                                     (float)(ws_size >> 20));
    return;
  }

  char* ws = (char*)d_ws;
  ushort_t* Kmat   = (ushort_t*)(ws);                // 33,554,432 B
  ushort_t* Vmat   = (ushort_t*)(ws + 33554432);     // 33,554,432 B
  float* pupd      = (float*)(ws + 67108864);        //  2,097,152 B
  float* pvsum     = (float*)(ws + 69206016);        //    262,144 B
  float* qbuf      = (float*)(ws + 69468160);        //    131,072 B
  float* snbuf     = (float*)(ws + 69599232);        //    131,072 B
  float* psum      = (float*)(ws + 69861376);        //     32,768 B

  k_lnproj<<<dim3(2048), dim3(256), 0, stream>>>(feats, gf, bfp, Wk, Wv, Kmat, Vmat);
  k_q0<<<dim3(B_*S_), dim3(64), 0, stream>>>(slots0, gs, bs, Wq, gf, snbuf, qbuf);
  for (int it=0; it<3; it++){
    k_attn<<<dim3(T_, B_), dim3(256), 0, stream>>>(Kmat, Vmat, qbuf, gf, pupd, psum, pvsum,
                                                   d_out, it==2?1:0);
    k_upd<<<dim3(B_*S_), dim3(256), 0, stream>>>(pupd, psum, pvsum, snbuf, qbuf, gf,
                                                 Wq, gs, bs, W_ih, W_hh, b_ih, b_hh,
                                                 gm, bm, W1, b1, W2, b2,
                                                 d_out, it==2?1:0);
  }
}